// Round 1
// baseline (395.075 us; speedup 1.0000x reference)
//
#include <hip/hip_runtime.h>
#include <hip/hip_bf16.h>

// Lfm2ShortConv decode: out = (Cg ⊙ conv_out) @ W2^T
//   Cg = x @ W1[D:2D]^T          (Bg,xg branches are dead — feed a discarded cache update)
//   conv_out[b,d] = sum_l conv_cache[0,b,d,l] * conv_w[d,0,l]
// B=2048, D=1024, L=3. Two bf16-MFMA GEMMs (2048x1024x1024) + fused gate.

#define BDIM 2048
#define DDIM 1024

typedef __attribute__((ext_vector_type(8))) short bf16x8;
typedef __attribute__((ext_vector_type(4))) float f32x4;

__device__ __forceinline__ unsigned short bf16rn(float f) {
    unsigned int u = __builtin_bit_cast(unsigned int, f);
    return (unsigned short)((u + 0x7FFFu + ((u >> 16) & 1u)) >> 16);
}

#define GLDS16(gp, lp)                                                          \
    __builtin_amdgcn_global_load_lds(                                           \
        (const __attribute__((address_space(1))) void*)(gp),                    \
        (__attribute__((address_space(3))) void*)(lp), 16, 0, 0)

// ---------------------------------------------------------------------------
// Kernel 1: cast x, W1c (=in_proj_w rows [D,2D)), W2 to bf16 (RNE) in d_ws.
// 1,048,576 float4 ops total; one float4 per thread.
// ---------------------------------------------------------------------------
__global__ __launch_bounds__(256) void prep_cast(
    const float* __restrict__ x, const float* __restrict__ w1,
    const float* __restrict__ w2, unsigned short* __restrict__ xb,
    unsigned short* __restrict__ w1b, unsigned short* __restrict__ w2b)
{
    const int t = blockIdx.x * 256 + threadIdx.x;
    const int X4 = BDIM * DDIM / 4;      // 524288
    const int W4 = DDIM * DDIM / 4;      // 262144
    float4 v;
    unsigned short* dst;
    if (t < X4) {
        v = ((const float4*)x)[t];
        dst = xb + (size_t)t * 4;
    } else if (t < X4 + W4) {
        int u = t - X4;
        v = ((const float4*)(w1 + (size_t)DDIM * DDIM))[u];   // rows [D, 2D)
        dst = w1b + (size_t)u * 4;
    } else {
        int u = t - X4 - W4;
        v = ((const float4*)w2)[u];
        dst = w2b + (size_t)u * 4;
    }
    ushort4 o;
    o.x = bf16rn(v.x); o.y = bf16rn(v.y); o.z = bf16rn(v.z); o.w = bf16rn(v.w);
    *(ushort4*)dst = o;
}

// ---------------------------------------------------------------------------
// Kernels 2/3: 64x64-tile bf16 GEMM, C = A(MxK) * B(NxK)^T, one wave/block.
// 4x4 grid of 16x16x32 MFMA tiles; BK=32; global_load_lds(16B) staging.
// GATE=true : epilogue multiplies by conv_out and stores bf16 to Ybf.
// GATE=false: epilogue stores fp32 to Yf32.
// ---------------------------------------------------------------------------
template <bool GATE>
__global__ __launch_bounds__(64) void gemm64(
    const unsigned short* __restrict__ A, const unsigned short* __restrict__ B,
    const float* __restrict__ cache,      // conv_cache layer 0: [B][D][3]
    const float* __restrict__ convw,      // [D][3]
    unsigned short* __restrict__ Ybf, float* __restrict__ Yf32, int K)
{
    __shared__ unsigned short ldsA[64 * 32];
    __shared__ unsigned short ldsB[64 * 32];

    const int lane = threadIdx.x;
    const int col  = lane & 15;
    const int quad = lane >> 4;
    const int m0   = blockIdx.y * 64;
    const int n0   = blockIdx.x * 64;

    // Staging: instruction t covers LDS bytes [t*1024, t*1024+1024);
    // HW writes lane's 16B at (uniform base + lane*16)  =>  lane l of chunk t
    // holds row (t*16 + l/4), k-elements [(l&3)*8, +8).  Row-major [64][32].
    const int rsub = lane >> 2;
    const int kel  = (lane & 3) * 8;
    const unsigned short* aSrc[4];
    const unsigned short* bSrc[4];
#pragma unroll
    for (int t = 0; t < 4; ++t) {
        aSrc[t] = A + (size_t)(m0 + t * 16 + rsub) * K + kel;
        bSrc[t] = B + (size_t)(n0 + t * 16 + rsub) * K + kel;
    }

    f32x4 acc[4][4] = {};

    for (int k0 = 0; k0 < K; k0 += 32) {
#pragma unroll
        for (int t = 0; t < 4; ++t) GLDS16(aSrc[t] + k0, &ldsA[t * 512]);
#pragma unroll
        for (int t = 0; t < 4; ++t) GLDS16(bSrc[t] + k0, &ldsB[t * 512]);
        __syncthreads();   // drain vmcnt: async LDS writes visible

        bf16x8 av[4], bv[4];
#pragma unroll
        for (int i = 0; i < 4; ++i)
            av[i] = *(const bf16x8*)&ldsA[(i * 16 + col) * 32 + quad * 8];
#pragma unroll
        for (int j = 0; j < 4; ++j)
            bv[j] = *(const bf16x8*)&ldsB[(j * 16 + col) * 32 + quad * 8];
#pragma unroll
        for (int i = 0; i < 4; ++i)
#pragma unroll
            for (int j = 0; j < 4; ++j)
                acc[i][j] = __builtin_amdgcn_mfma_f32_16x16x32_bf16(
                    av[i], bv[j], acc[i][j], 0, 0, 0);
        __syncthreads();   // reads done before next stage overwrites
    }

    // Epilogue. C/D mapping (HW-verified): row = quad*4 + r, col = lane&15.
#pragma unroll
    for (int j = 0; j < 4; ++j) {
        const int n = n0 + j * 16 + col;
        float cw0, cw1, cw2;
        if (GATE) {
            cw0 = convw[n * 3 + 0];
            cw1 = convw[n * 3 + 1];
            cw2 = convw[n * 3 + 2];
        }
#pragma unroll
        for (int i = 0; i < 4; ++i) {
#pragma unroll
            for (int r = 0; r < 4; ++r) {
                const int m = m0 + i * 16 + quad * 4 + r;
                const float v = acc[i][j][r];
                if (GATE) {
                    const float* cp = cache + ((size_t)m * DDIM + n) * 3;
                    const float co = cp[0] * cw0 + cp[1] * cw1 + cp[2] * cw2;
                    Ybf[(size_t)m * DDIM + n] = bf16rn(v * co);
                } else {
                    Yf32[(size_t)m * DDIM + n] = v;
                }
            }
        }
    }
}

// ---------------------------------------------------------------------------
extern "C" void kernel_launch(void* const* d_in, const int* in_sizes, int n_in,
                              void* d_out, int out_size, void* d_ws, size_t ws_size,
                              hipStream_t stream)
{
    const float* x     = (const float*)d_in[0];
    const float* cache = (const float*)d_in[1];   // layer 0 is at offset 0
    const float* w1    = (const float*)d_in[3];
    const float* w2    = (const float*)d_in[4];
    const float* cw    = (const float*)d_in[5];
    float* out = (float*)d_out;

    unsigned short* xb  = (unsigned short*)d_ws;            // 4 MB
    unsigned short* w1b = xb  + (size_t)BDIM * DDIM;        // 2 MB
    unsigned short* w2b = w1b + (size_t)DDIM * DDIM;        // 2 MB
    unsigned short* yb  = w2b + (size_t)DDIM * DDIM;        // 4 MB (12 MB total)

    prep_cast<<<dim3(4096), dim3(256), 0, stream>>>(x, w1, w2, xb, w1b, w2b);

    dim3 grid(DDIM / 64, BDIM / 64);  // 16 x 32 = 512 blocks
    gemm64<true><<<grid, dim3(64), 0, stream>>>(xb, w1b, cache, cw, yb, nullptr, DDIM);
    gemm64<false><<<grid, dim3(64), 0, stream>>>(yb, w2b, nullptr, nullptr, nullptr, out, DDIM);
}

// Round 2
// 377.481 us; speedup vs baseline: 1.0466x; 1.0466x over previous
//
#include <hip/hip_runtime.h>
#include <hip/hip_bf16.h>

// Lfm2ShortConv decode: out = (Cg ⊙ conv_out) @ W2^T
//   Cg = x @ W1[D:2D]^T          (Bg,xg branches are dead — feed a discarded cache update)
//   conv_out[b,d] = sum_l conv_cache[0,b,d,l] * conv_w[d,0,l]
// M=2048 (batch), N=K=1024. Two bf16-MFMA GEMMs + gate fused in GEMM1 epilogue.
//
// Structure (round 2): 64x64 block tile, 128 threads (2 waves), each wave a
// 64(M)x32(N) subtile => 6 ds_read_b128 : 8 MFMA per 32-k-step (LDS ceiling
// ~1.12 PF). 512 blocks = 2 blocks/CU; cross-block overlap hides the
// vmcnt(0)+barrier drain. BK=64, XOR-swizzled LDS so every ds_read_b128 is
// conflict-free under the glds fixed lane->lane*16 placement.

#define MDIM 2048
#define NDIM 1024
#define KDIM 1024

typedef __attribute__((ext_vector_type(8))) short bf16x8;
typedef __attribute__((ext_vector_type(4))) float f32x4;

__device__ __forceinline__ unsigned short bf16rn(float f) {
    unsigned int u = __builtin_bit_cast(unsigned int, f);
    return (unsigned short)((u + 0x7FFFu + ((u >> 16) & 1u)) >> 16);
}

#define GLDS16(gp, lp)                                                          \
    __builtin_amdgcn_global_load_lds(                                           \
        (const __attribute__((address_space(1))) void*)(gp),                    \
        (__attribute__((address_space(3))) void*)(lp), 16, 0, 0)

// ---------------------------------------------------------------------------
// Kernel 1: cast x, W1c (=in_proj_w rows [D,2D)), W2 to bf16 (RNE) in d_ws.
// ---------------------------------------------------------------------------
__global__ __launch_bounds__(256) void prep_cast(
    const float* __restrict__ x, const float* __restrict__ w1,
    const float* __restrict__ w2, unsigned short* __restrict__ xb,
    unsigned short* __restrict__ w1b, unsigned short* __restrict__ w2b)
{
    const int t = blockIdx.x * 256 + threadIdx.x;
    const int X4 = MDIM * KDIM / 4;      // 524288
    const int W4 = KDIM * NDIM / 4;      // 262144
    float4 v;
    unsigned short* dst;
    if (t < X4) {
        v = ((const float4*)x)[t];
        dst = xb + (size_t)t * 4;
    } else if (t < X4 + W4) {
        int u = t - X4;
        v = ((const float4*)(w1 + (size_t)NDIM * KDIM))[u];   // rows [D, 2D)
        dst = w1b + (size_t)u * 4;
    } else {
        int u = t - X4 - W4;
        v = ((const float4*)w2)[u];
        dst = w2b + (size_t)u * 4;
    }
    ushort4 o;
    o.x = bf16rn(v.x); o.y = bf16rn(v.y); o.z = bf16rn(v.z); o.w = bf16rn(v.w);
    *(ushort4*)dst = o;
}

// ---------------------------------------------------------------------------
// GEMM: C[M x N] = A[M x K] * B[N x K]^T, bf16 inputs, fp32 accumulate.
// Block = 64x64 tile, 2 waves; wave w handles n-half w (64x32 subtile).
// LDS layout: [64 rows][8 slots][8 elems]; slot s of row r holds k-group
// s ^ (r&7) — matches glds lane->base+lane*16 placement with per-lane source
// addresses, and makes fragment ds_read_b128 8-phase conflict-free.
// ---------------------------------------------------------------------------
template <bool GATE>
__global__ __launch_bounds__(128) void gemm(
    const unsigned short* __restrict__ A, const unsigned short* __restrict__ Bm,
    const float* __restrict__ cache,      // conv_cache layer 0: [M][N][3]
    const float* __restrict__ convw,      // [N][3]
    unsigned short* __restrict__ Ybf, float* __restrict__ Yout)
{
    __shared__ unsigned short ldsA[64 * 64];
    __shared__ unsigned short ldsB[64 * 64];

    const int tid  = threadIdx.x;
    const int lane = tid & 63;
    const int w    = tid >> 6;           // wave 0..1
    const int col  = lane & 15;
    const int quad = lane >> 4;
    const int m0   = blockIdx.y * 64;
    const int n0   = blockIdx.x * 64;

    // Staging: chunk c (1 KiB) = rows [8c, 8c+8). Lane l writes 16 B at
    // c*1024 + l*16 => row 8c + (l>>3), slot l&7, which must hold k-group
    // (l&7) ^ ((l>>3)&7). Wave w stages chunks 4w..4w+3 of A and B.
    const int rsub = lane >> 3;
    const int kg   = (lane & 7) ^ rsub;
    size_t aoff[4], boff[4];
#pragma unroll
    for (int t = 0; t < 4; ++t) {
        const int c = 4 * w + t;
        aoff[t] = (size_t)(m0 + 8 * c + rsub) * KDIM + kg * 8;
        boff[t] = (size_t)(n0 + 8 * c + rsub) * KDIM + kg * 8;
    }

    f32x4 acc[4][2] = {};

    for (int k0 = 0; k0 < KDIM; k0 += 64) {
#pragma unroll
        for (int t = 0; t < 4; ++t) {
            const int c = 4 * w + t;
            GLDS16(A + aoff[t] + k0, &ldsA[c * 512]);
            GLDS16(Bm + boff[t] + k0, &ldsB[c * 512]);
        }
        __syncthreads();   // drain vmcnt: async LDS writes visible

#pragma unroll
        for (int ks = 0; ks < 2; ++ks) {
            const int slot = (ks * 4 + quad) ^ (col & 7);
            bf16x8 av[4], bv[2];
#pragma unroll
            for (int i = 0; i < 4; ++i)
                av[i] = *(const bf16x8*)&ldsA[(i * 16 + col) * 64 + slot * 8];
#pragma unroll
            for (int j = 0; j < 2; ++j)
                bv[j] = *(const bf16x8*)&ldsB[(w * 32 + j * 16 + col) * 64 + slot * 8];
#pragma unroll
            for (int i = 0; i < 4; ++i)
#pragma unroll
                for (int j = 0; j < 2; ++j)
                    acc[i][j] = __builtin_amdgcn_mfma_f32_16x16x32_bf16(
                        av[i], bv[j], acc[i][j], 0, 0, 0);
        }
        __syncthreads();   // reads done before next stage overwrites
    }

    // Epilogue. C/D mapping (HW-verified): row = quad*4 + r, col = lane&15.
#pragma unroll
    for (int j = 0; j < 2; ++j) {
        const int n = n0 + w * 32 + j * 16 + col;
        float cw0, cw1, cw2;
        if (GATE) {
            cw0 = convw[n * 3 + 0];
            cw1 = convw[n * 3 + 1];
            cw2 = convw[n * 3 + 2];
        }
#pragma unroll
        for (int i = 0; i < 4; ++i) {
#pragma unroll
            for (int r = 0; r < 4; ++r) {
                const int m = m0 + i * 16 + quad * 4 + r;
                float v = acc[i][j][r];
                if (GATE) {
                    const float* cp = cache + ((size_t)m * NDIM + n) * 3;
                    v *= cp[0] * cw0 + cp[1] * cw1 + cp[2] * cw2;
                    Ybf[(size_t)m * NDIM + n] = bf16rn(v);
                } else {
                    Yout[(size_t)m * NDIM + n] = v;
                }
            }
        }
    }
}

// ---------------------------------------------------------------------------
extern "C" void kernel_launch(void* const* d_in, const int* in_sizes, int n_in,
                              void* d_out, int out_size, void* d_ws, size_t ws_size,
                              hipStream_t stream)
{
    const float* x     = (const float*)d_in[0];
    const float* cache = (const float*)d_in[1];   // layer 0 is at offset 0
    const float* w1    = (const float*)d_in[3];
    const float* w2    = (const float*)d_in[4];
    const float* cw    = (const float*)d_in[5];
    float* out = (float*)d_out;

    unsigned short* xb  = (unsigned short*)d_ws;            // 4 MB
    unsigned short* w1b = xb  + (size_t)MDIM * KDIM;        // 2 MB
    unsigned short* w2b = w1b + (size_t)KDIM * NDIM;        // 2 MB
    unsigned short* yb  = w2b + (size_t)KDIM * NDIM;        // 4 MB (12 MB total)

    prep_cast<<<dim3(4096), dim3(256), 0, stream>>>(x, w1, w2, xb, w1b, w2b);

    dim3 grid(NDIM / 64, MDIM / 64);  // 16 x 32 = 512 blocks, 128 thr each
    gemm<true><<<grid, dim3(128), 0, stream>>>(xb, w1b, cache, cw, yb, nullptr);
    gemm<false><<<grid, dim3(128), 0, stream>>>(yb, w2b, nullptr, nullptr, nullptr, out);
}